// Round 2
// baseline (50.353 us; speedup 1.0000x reference)
//
#include <hip/hip_runtime.h>

// SymbolicTraversal: out[b, n] = max(0, max_{e: type[e]==r_index[b], dst[e]==n} h[b, src[e]])
// R1: nontemporal streaming of edge data (keep L2 for h/out), unconditional upfront
// src/dst loads (MLP), split gather/atomic passes, custom zero-fill kernel.

typedef int v4i __attribute__((ext_vector_type(4)));

__global__ __launch_bounds__(256)
void zero_kernel(float4* __restrict__ out, int n4) {
    int i = blockIdx.x * blockDim.x + threadIdx.x;
    if (i < n4) {
        float4 z; z.x = 0.f; z.y = 0.f; z.z = 0.f; z.w = 0.f;
        out[i] = z;
    }
}

__global__ __launch_bounds__(256)
void traverse_kernel(const float* __restrict__ h,
                     const int* __restrict__ edge_index, // [2][E]
                     const int* __restrict__ etype,      // [E]
                     const int* __restrict__ r_index,    // [B]
                     int* __restrict__ out,              // [B][N] as int bits
                     int B, int N, int E) {
    __shared__ unsigned int smask[64];
    if (threadIdx.x < 64) {
        unsigned int m = 0;
        for (int b = 0; b < B; ++b)
            if (r_index[b] == (int)threadIdx.x) m |= (1u << b);
        smask[threadIdx.x] = m;
    }
    __syncthreads();

    const int* __restrict__ src = edge_index;
    const int* __restrict__ dst = edge_index + E;

    int tid = blockIdx.x * blockDim.x + threadIdx.x;
    int e4 = tid * 4;

    if (e4 + 3 < E) {
        // Issue all three streaming loads back-to-back, nontemporal (no L2 pollution).
        v4i t = __builtin_nontemporal_load(reinterpret_cast<const v4i*>(etype + e4));
        v4i s = __builtin_nontemporal_load(reinterpret_cast<const v4i*>(src + e4));
        v4i d = __builtin_nontemporal_load(reinterpret_cast<const v4i*>(dst + e4));

        unsigned int m[4];
        #pragma unroll
        for (int i = 0; i < 4; ++i) {
            unsigned int tt = (unsigned int)t[i];
            m[i] = (tt < 64u) ? smask[tt] : 0u;
        }

        // Pass A: issue all first-bit h gathers independently.
        float v0[4]; int b0[4];
        #pragma unroll
        for (int i = 0; i < 4; ++i) {
            if (m[i]) {
                b0[i] = __builtin_ctz(m[i]);
                v0[i] = h[(size_t)b0[i] * N + s[i]];
            }
        }

        // Pass B: atomics (fire-and-forget) + rare multi-bit slow path.
        #pragma unroll
        for (int i = 0; i < 4; ++i) {
            if (m[i]) {
                if (v0[i] > 0.0f)
                    atomicMax(out + (size_t)b0[i] * N + d[i], __float_as_int(v0[i]));
                unsigned int rem = m[i] & (m[i] - 1);
                while (rem) {
                    int b = __builtin_ctz(rem);
                    rem &= rem - 1;
                    float v = h[(size_t)b * N + s[i]];
                    if (v > 0.0f)
                        atomicMax(out + (size_t)b * N + d[i], __float_as_int(v));
                }
            }
        }
    } else if (e4 < E) {
        for (int e = e4; e < E; ++e) {
            unsigned int tt = (unsigned int)etype[e];
            unsigned int mm = (tt < 64u) ? smask[tt] : 0u;
            while (mm) {
                int b = __builtin_ctz(mm);
                mm &= mm - 1;
                float v = h[(size_t)b * N + src[e]];
                if (v > 0.0f)
                    atomicMax(out + (size_t)b * N + dst[e], __float_as_int(v));
            }
        }
    }
}

extern "C" void kernel_launch(void* const* d_in, const int* in_sizes, int n_in,
                              void* d_out, int out_size, void* d_ws, size_t ws_size,
                              hipStream_t stream) {
    const float* h          = (const float*)d_in[0];
    const int*   edge_index = (const int*)d_in[1];
    const int*   etype      = (const int*)d_in[2];
    const int*   r_index    = (const int*)d_in[3];

    const int B = in_sizes[3];
    const int N = in_sizes[0] / B;
    const int E = in_sizes[2];

    // out = 0.0f everywhere (handles empty segments + clamp(min=0) floor)
    const int n4 = out_size / 4;
    zero_kernel<<<(n4 + 255) / 256, 256, 0, stream>>>((float4*)d_out, n4);

    const int threads = 256;
    const int nquads  = (E + 3) / 4;
    const int blocks  = (nquads + threads - 1) / threads;

    traverse_kernel<<<blocks, threads, 0, stream>>>(
        h, edge_index, etype, r_index, (int*)d_out, B, N, E);
}